// Round 8
// baseline (492.835 us; speedup 1.0000x reference)
//
#include <hip/hip_runtime.h>
#include <math.h>

typedef _Float16 f16x8 __attribute__((ext_vector_type(8)));
typedef _Float16 f16x4 __attribute__((ext_vector_type(4)));
typedef float    f32x4 __attribute__((ext_vector_type(4)));

#define B_TOT 2048
#define LSEQ  512
#define NS    16          // samples per group (MFMA N)
#define NG    2           // groups per workgroup, one per 4-wave set
#define HS    88          // f16 per sample row of Hh (176 B)
#define LOG2E 1.44269504088896f
#define LN2   0.69314718055995f

#define MFMA16(A, B, C) __builtin_amdgcn_mfma_f32_16x16x32_f16((A), (B), (C), 0, 0, 0)

// Per-group split barrier: slot-per-wave arrive, acquire-poll until all 4 waves
// reached phase v+1. Decouples the two groups' step phases (unlike s_barrier).
__device__ __forceinline__ void group_arrive_wait(int* slots, int w, int v, int lane) {
    if (lane == 0)
        __hip_atomic_store(&slots[w], v + 1, __ATOMIC_RELEASE, __HIP_MEMORY_SCOPE_WORKGROUP);
    for (;;) {
        int s0 = __hip_atomic_load(&slots[0], __ATOMIC_ACQUIRE, __HIP_MEMORY_SCOPE_WORKGROUP);
        int s1 = __hip_atomic_load(&slots[1], __ATOMIC_ACQUIRE, __HIP_MEMORY_SCOPE_WORKGROUP);
        int s2 = __hip_atomic_load(&slots[2], __ATOMIC_ACQUIRE, __HIP_MEMORY_SCOPE_WORKGROUP);
        int s3 = __hip_atomic_load(&slots[3], __ATOMIC_ACQUIRE, __HIP_MEMORY_SCOPE_WORKGROUP);
        if (s0 > v && s1 > v && s2 > v && s3 > v) break;
    }
}

__global__ __launch_bounds__(512, 1)
void lstm_sb_kernel(const int* __restrict__ s,
                    const float* __restrict__ W0, const float* __restrict__ b0,
                    const float* __restrict__ Wi, const float* __restrict__ Wh,
                    const float* __restrict__ bh, const float* __restrict__ Wa,
                    const float* __restrict__ ba, const float* __restrict__ Wp,
                    const float* __restrict__ bp, float* __restrict__ out)
{
    const int tid  = threadIdx.x;
    const int wave = tid >> 6;       // 0..7
    const int grp  = wave >> 2;      // 0..1 — independent group per 4-wave set
    const int w    = wave & 3;       // feature block 16w..16w+15 within the group
    const int lane = tid & 63;
    const int n    = lane & 15;      // sample within group
    const int q    = lane >> 4;
    const int b0s  = blockIdx.x * (NS * NG);

    __shared__ __align__(16) _Float16 Hh[2][NG][NS * HS];   // 11264 B
    __shared__ unsigned short TOKB[NG][LSEQ + 2];           //  2056 B
    __shared__ unsigned char  SRAW[NG * NS][LSEQ];          // 16384 B
    __shared__ _Float16 DBUF[NG][LSEQ][NS];                 // 32768 B
    __shared__ float PART[NG][16][NS];                      //  2048 B
    __shared__ int BAR[NG][4];                              //    32 B

    if (tid < NG * 4) BAR[tid >> 2][tid & 3] = 0;

    // ---- stage tokens (coalesced in t) ----
    for (int i = tid; i < NG * NS * LSEQ; i += 512)
        SRAW[i >> 9][i & 511] = (unsigned char)s[(b0s + (i >> 9)) * LSEQ + (i & 511)];
    __syncthreads();
    for (int u = tid; u <= LSEQ; u += 512) {
        #pragma unroll
        for (int g = 0; g < NG; ++g) {
            unsigned int mask = 0;
            if (u >= 1) {
                #pragma unroll
                for (int m = 0; m < NS; ++m)
                    mask |= ((unsigned int)SRAW[g * NS + m][u - 1]) << m;
            }
            TOKB[g][u] = (unsigned short)mask;
        }
    }

    // ---- A-frags: scaled Wh^T (per wave; depends only on w) ----
    f16x8 awh[4][2];
    #pragma unroll
    for (int gg = 0; gg < 4; ++gg) {
        const float sc  = (gg == 2) ? (2.0f * LOG2E) : (-LOG2E);
        const int   col = 64 * gg + 16 * w + n;
        #pragma unroll
        for (int c = 0; c < 2; ++c)
            #pragma unroll
            for (int j = 0; j < 8; ++j)
                awh[gg][c][j] = (_Float16)(Wh[(32 * c + 8 * q + j) * 256 + col] * sc);
    }

    // ---- d-GEMM A-frag: row 0 = Wa[:,1]-Wa[:,0] ----
    f16x8 awd[2];
    #pragma unroll
    for (int c = 0; c < 2; ++c)
        #pragma unroll
        for (int j = 0; j < 8; ++j) {
            int k = 32 * c + 8 * q + j;
            awd[c][j] = (_Float16)((n == 0) ? (Wa[2 * k + 1] - Wa[2 * k]) : 0.0f);
        }
    const float dba = ba[1] - ba[0];

    // ---- p0/dp (scaled) ----
    float p0v[4][4], dpv[4][4];
    {
        float a0[4][4], a1[4][4];
        #pragma unroll
        for (int gg = 0; gg < 4; ++gg)
            #pragma unroll
            for (int r = 0; r < 4; ++r) {
                float bb = bh[64 * gg + 16 * w + 4 * q + r];
                a0[gg][r] = bb; a1[gg][r] = bb;
            }
        for (int f = 0; f < 64; ++f) {
            float wb0 = W0[f]      + b0[f];
            float wb1 = W0[64 + f] + b0[f];
            #pragma unroll
            for (int gg = 0; gg < 4; ++gg) {
                const float4 wi4 = *(const float4*)&Wi[f * 256 + 64 * gg + 16 * w + 4 * q];
                #pragma unroll
                for (int r = 0; r < 4; ++r) {
                    float wi = (&wi4.x)[r];
                    a0[gg][r] = fmaf(wb0, wi, a0[gg][r]);
                    a1[gg][r] = fmaf(wb1, wi, a1[gg][r]);
                }
            }
        }
        #pragma unroll
        for (int gg = 0; gg < 4; ++gg) {
            const float sc = (gg == 2) ? (2.0f * LOG2E) : (-LOG2E);
            #pragma unroll
            for (int r = 0; r < 4; ++r) {
                p0v[gg][r] = a0[gg][r] * sc;
                dpv[gg][r] = (a1[gg][r] - a0[gg][r]) * sc;
            }
        }
    }

    __syncthreads();   // TOKB/BAR ready — last workgroup-wide barrier before tail

    // phase stagger: push group 1 ~half a step out of phase so the two chains'
    // stall/burst windows interleave on each SIMD (they then stay offset)
    if (grp == 1) __builtin_amdgcn_s_sleep(4);

    // ---- state ----
    float h4[4] = {0, 0, 0, 0}, c4[4] = {0, 0, 0, 0};
    f32x4 ci[4];
    #pragma unroll
    for (int gg = 0; gg < 4; ++gg)
        ci[gg] = (f32x4){p0v[gg][0], p0v[gg][1], p0v[gg][2], p0v[gg][3]};

    int* const bar = &BAR[grp][0];

    #pragma unroll 1
    for (int v = 0; v <= LSEQ; ++v) {
        const int p = v & 1;

        // publish h_{v-1}
        f16x4 hv;
        #pragma unroll
        for (int r = 0; r < 4; ++r) hv[r] = (_Float16)h4[r];
        *(f16x4*)&Hh[p][grp][n * HS + 16 * w + 4 * q] = hv;

        group_arrive_wait(bar, w, v, lane);

        // B-frags of h_{v-1} (this group)
        f16x8 bf0 = *(const f16x8*)&Hh[p][grp][n * HS + 8 * q];
        f16x8 bf1 = *(const f16x8*)&Hh[p][grp][n * HS + 32 + 8 * q];

        const unsigned int tokm_next = (v < LSEQ) ? (unsigned int)TOKB[grp][v + 1] : 0u;

        // gates GEMM
        f32x4 acc0 = ci[0], acc1 = ci[1], acc2 = ci[2], acc3 = ci[3];
        acc0 = MFMA16(awh[0][0], bf0, acc0);
        acc1 = MFMA16(awh[1][0], bf0, acc1);
        acc2 = MFMA16(awh[2][0], bf0, acc2);
        acc3 = MFMA16(awh[3][0], bf0, acc3);
        acc0 = MFMA16(awh[0][1], bf1, acc0);
        acc1 = MFMA16(awh[1][1], bf1, acc1);
        acc2 = MFMA16(awh[2][1], bf1, acc2);
        acc3 = MFMA16(awh[3][1], bf1, acc3);

        // rotating straggler, offset per group so both never hit the same SIMD
        if (v >= 1 && w == ((v + 2 * grp) & 3)) {
            f32x4 da = (f32x4){dba, dba, dba, dba};
            da = MFMA16(awd[0], bf0, da);
            da = MFMA16(awd[1], bf1, da);
            if (lane < 16) DBUF[grp][v - 1][n] = (_Float16)da[0];
        }

        // C-init for next iter
        const float sel = (float)((tokm_next >> n) & 1u);
        #pragma unroll
        for (int gg = 0; gg < 4; ++gg)
            #pragma unroll
            for (int r = 0; r < 4; ++r)
                ci[gg][r] = fmaf(sel, dpv[gg][r], p0v[gg][r]);

        // activations
        #pragma unroll
        for (int r = 0; r < 4; ++r) {
            float ei = __builtin_amdgcn_exp2f(acc0[r]);               // e^{-i}
            float ef = __builtin_amdgcn_exp2f(acc1[r]);               // e^{-f}
            float eg = __builtin_amdgcn_exp2f(fminf(acc2[r], 60.f));  // e^{2g}
            float eo = __builtin_amdgcn_exp2f(acc3[r]);               // e^{-o}
            float Rf  = __builtin_amdgcn_rcpf(1.0f + ef);
            float Rig = __builtin_amdgcn_rcpf((1.0f + ei) * (eg + 1.0f));
            float cn  = fmaf(c4[r], Rf, (eg - 1.0f) * Rig);
            c4[r] = cn;
            float ec = __builtin_amdgcn_exp2f(fminf(cn * (2.0f * LOG2E), 60.f));
            float Ro = __builtin_amdgcn_rcpf((1.0f + eo) * (ec + 1.0f));
            h4[r] = (ec - 1.0f) * Ro;
        }
    }

    // ---- tail: publish h_512 (Hh[1] is free: last iter used p=0) ----
    {
        f16x4 hv;
        #pragma unroll
        for (int r = 0; r < 4; ++r) hv[r] = (_Float16)h4[r];
        *(f16x4*)&Hh[1][grp][n * HS + 16 * w + 4 * q] = hv;
    }
    __syncthreads();   // both groups done; DBUF + final Hh visible to all

    // ---- amp post-pass: 512 threads, 32 softplus terms each ----
    {
        const int g  = tid >> 8;            // 0..1
        const int nn = tid & 15;
        const int ch = (tid >> 4) & 15;     // 16 chunks of 32 steps
        float a = 0.0f;
        #pragma unroll 4
        for (int k = 0; k < 32; ++k) {
            int t = ch * 32 + k;
            float d = (float)DBUF[g][t][nn];
            float x = SRAW[g * NS + nn][t] ? -d : d;
            float e = __builtin_amdgcn_exp2f(-fabsf(x) * LOG2E);
            a += fmaxf(x, 0.0f) + __builtin_amdgcn_logf(1.0f + e) * LN2;
        }
        PART[g][ch][nn] = a;
    }
    __syncthreads();

    if (tid < 16 * NG) {
        const int g = tid >> 4, nn = tid & 15;
        float ssum = 0.0f;
        #pragma unroll
        for (int c = 0; c < 16; ++c) ssum += PART[g][c][nn];
        out[b0s + g * NS + nn] = -0.5f * ssum;      // planar real
    }

    // ---- phase: wave 0 of each group ----
    if (w == 0) {
        const _Float16* hp = &Hh[1][grp][n * HS + 16 * q];
        f16x8 h0 = *(const f16x8*)hp;
        f16x8 h1 = *(const f16x8*)(hp + 8);
        float ph = 0.0f;
        #pragma unroll
        for (int j = 0; j < 8; ++j)
            ph = fmaf((float)h0[j], Wp[16 * q + j],
                 fmaf((float)h1[j], Wp[16 * q + j + 8], ph));
        ph += __shfl_xor(ph, 16, 64);
        ph += __shfl_xor(ph, 32, 64);
        if (q == 0) out[B_TOT + b0s + grp * NS + n] = ph + bp[0];   // planar imag
    }
}

extern "C" void kernel_launch(void* const* d_in, const int* in_sizes, int n_in,
                              void* d_out, int out_size, void* d_ws, size_t ws_size,
                              hipStream_t stream) {
    const int*   s  = (const int*)  d_in[0];
    const float* W0 = (const float*)d_in[1];
    const float* b0 = (const float*)d_in[2];
    const float* Wi = (const float*)d_in[3];
    const float* Wh = (const float*)d_in[4];
    const float* bh = (const float*)d_in[5];
    const float* Wa = (const float*)d_in[6];
    const float* ba = (const float*)d_in[7];
    const float* Wp = (const float*)d_in[8];
    const float* bp = (const float*)d_in[9];
    float* out = (float*)d_out;

    dim3 grid(B_TOT / (NS * NG));   // 64 WGs × 512 thr: 2 phase-decoupled chains/SIMD
    dim3 block(512);
    lstm_sb_kernel<<<grid, block, 0, stream>>>(s, W0, b0, Wi, Wh, bh,
                                               Wa, ba, Wp, bp, out);
}

// Round 10
// 339.028 us; speedup vs baseline: 1.4537x; 1.4537x over previous
//
#include <hip/hip_runtime.h>
#include <math.h>

typedef _Float16 f16x8 __attribute__((ext_vector_type(8)));
typedef float    f32x4 __attribute__((ext_vector_type(4)));
typedef _Float16 f16x2 __attribute__((ext_vector_type(2)));
typedef __fp16   fp16x2 __attribute__((ext_vector_type(2)));

#define B_TOT 2048
#define LSEQ  512
#define NS    16
#define LOG2E 1.44269504088896f
#define LN2   0.69314718055995f

#define MFMA16(A, B, C) __builtin_amdgcn_mfma_f32_16x16x32_f16((A), (B), (C), 0, 0, 0)

__device__ __forceinline__ unsigned int pkrtz(float a, float b) {
    fp16x2 p = __builtin_amdgcn_cvt_pkrtz(a, b);
    return __builtin_bit_cast(unsigned int, p);
}

__global__ __launch_bounds__(256, 1)
void lstm_bank_kernel(const int* __restrict__ s,
                      const float* __restrict__ W0, const float* __restrict__ b0,
                      const float* __restrict__ Wi, const float* __restrict__ Wh,
                      const float* __restrict__ bh, const float* __restrict__ Wa,
                      const float* __restrict__ ba, const float* __restrict__ Wp,
                      const float* __restrict__ bp, float* __restrict__ out)
{
    const int tid  = threadIdx.x;
    const int w    = tid >> 6;     // wave 0..3: feature block 16w..16w+15 (all 4 gates)
    const int lane = tid & 63;
    const int n    = lane & 15;    // sample (MFMA N / D-col)
    const int q    = lane >> 4;
    const int b0s  = blockIdx.x * NS;

    // h store: dword j (features 8c+2j,+1) of chunk c (features 8c..8c+7) of
    // sample n lives at dword address n + 16*(c&1) + 32*j + 128*(c>>1).
    // Every wave64 LDS phase then hits banks (n + 16*(c&1)) — 2 lanes/bank: FREE.
    __shared__ unsigned int  HhD[2][512];           //  4 KB
    __shared__ unsigned short TOKB[LSEQ + 2];       //  1 KB
    __shared__ unsigned char  SRAW[NS][LSEQ];       //  8 KB
    __shared__ _Float16 DBUF[LSEQ][NS];             // 16 KB
    __shared__ float PART[16][NS];                  //  1 KB

    // ---- stage tokens (coalesced in t) ----
    for (int i = tid; i < NS * LSEQ; i += 256)
        SRAW[i >> 9][i & 511] = (unsigned char)s[(b0s + (i >> 9)) * LSEQ + (i & 511)];
    __syncthreads();
    for (int u = tid; u <= LSEQ; u += 256) {
        unsigned int mask = 0;
        if (u >= 1) {
            #pragma unroll
            for (int m = 0; m < NS; ++m)
                mask |= ((unsigned int)SRAW[m][u - 1]) << m;
        }
        TOKB[u] = (unsigned short)mask;
    }

    // ---- A-frags: scaled Wh^T ----
    f16x8 awh[4][2];
    #pragma unroll
    for (int g = 0; g < 4; ++g) {
        const float sc  = (g == 2) ? (2.0f * LOG2E) : (-LOG2E);
        const int   col = 64 * g + 16 * w + n;
        #pragma unroll
        for (int c = 0; c < 2; ++c)
            #pragma unroll
            for (int j = 0; j < 8; ++j)
                awh[g][c][j] = (_Float16)(Wh[(32 * c + 8 * q + j) * 256 + col] * sc);
    }

    // ---- d-GEMM A-frag: row 0 = Wa[:,1]-Wa[:,0] ----
    f16x8 awd[2];
    #pragma unroll
    for (int c = 0; c < 2; ++c)
        #pragma unroll
        for (int j = 0; j < 8; ++j) {
            int k = 32 * c + 8 * q + j;
            awd[c][j] = (_Float16)((n == 0) ? (Wa[2 * k + 1] - Wa[2 * k]) : 0.0f);
        }
    const float dba = ba[1] - ba[0];

    // ---- p0/dp (scaled) ----
    float p0v[4][4], dpv[4][4];
    {
        float a0[4][4], a1[4][4];
        #pragma unroll
        for (int g = 0; g < 4; ++g)
            #pragma unroll
            for (int r = 0; r < 4; ++r) {
                float bb = bh[64 * g + 16 * w + 4 * q + r];
                a0[g][r] = bb; a1[g][r] = bb;
            }
        for (int f = 0; f < 64; ++f) {
            float wb0 = W0[f]      + b0[f];
            float wb1 = W0[64 + f] + b0[f];
            #pragma unroll
            for (int g = 0; g < 4; ++g) {
                const float4 wi4 = *(const float4*)&Wi[f * 256 + 64 * g + 16 * w + 4 * q];
                #pragma unroll
                for (int r = 0; r < 4; ++r) {
                    float wi = (&wi4.x)[r];
                    a0[g][r] = fmaf(wb0, wi, a0[g][r]);
                    a1[g][r] = fmaf(wb1, wi, a1[g][r]);
                }
            }
        }
        #pragma unroll
        for (int g = 0; g < 4; ++g) {
            const float sc = (g == 2) ? (2.0f * LOG2E) : (-LOG2E);
            #pragma unroll
            for (int r = 0; r < 4; ++r) {
                p0v[g][r] = a0[g][r] * sc;
                dpv[g][r] = (a1[g][r] - a0[g][r]) * sc;
            }
        }
    }

    __syncthreads();   // TOKB ready

    // ---- loop-invariant LDS dword addresses ----
    // publish: lane (n,q,w) -> chunk c=2w+(q>>1), dwords j=2*(q&1), +1
    const int wAddr = n + 16 * (q >> 1) + 64 * (q & 1) + 128 * w;
    // read: bf0 chunk q -> base n+16*(q&1)+128*(q>>1); bf1 chunk 4+q -> +256
    const int rAddr = n + 16 * (q & 1) + 128 * (q >> 1);

    // ---- state ----
    float h4[4] = {0, 0, 0, 0}, c4[4] = {0, 0, 0, 0};
    f32x4 ci[4];
    #pragma unroll
    for (int g = 0; g < 4; ++g)
        ci[g] = (f32x4){p0v[g][0], p0v[g][1], p0v[g][2], p0v[g][3]};

    #pragma unroll 1
    for (int v = 0; v <= LSEQ; ++v) {
        const int p = v & 1;
        unsigned int* __restrict__ hb = &HhD[p][0];

        // publish h_{v-1}: two dwords, banks n+16*(q>>1) -> 2-way (free)
        hb[wAddr]      = pkrtz(h4[0], h4[1]);
        hb[wAddr + 32] = pkrtz(h4[2], h4[3]);
        __syncthreads();

        // B-frags: 8 dword reads, every phase banks n+16*(q&1) -> 2-way (free)
        union { f16x8 v; unsigned int u[4]; } bf0u, bf1u;
        #pragma unroll
        for (int j = 0; j < 4; ++j) {
            bf0u.u[j] = hb[rAddr +       32 * j];
            bf1u.u[j] = hb[rAddr + 256 + 32 * j];
        }
        const f16x8 bf0 = bf0u.v, bf1 = bf1u.v;

        const unsigned int tokm_next = (v < LSEQ) ? (unsigned int)TOKB[v + 1] : 0u;

        // gates GEMM
        f32x4 acc0 = ci[0], acc1 = ci[1], acc2 = ci[2], acc3 = ci[3];
        acc0 = MFMA16(awh[0][0], bf0, acc0);
        acc1 = MFMA16(awh[1][0], bf0, acc1);
        acc2 = MFMA16(awh[2][0], bf0, acc2);
        acc3 = MFMA16(awh[3][0], bf0, acc3);
        acc0 = MFMA16(awh[0][1], bf1, acc0);
        acc1 = MFMA16(awh[1][1], bf1, acc1);
        acc2 = MFMA16(awh[2][1], bf1, acc2);
        acc3 = MFMA16(awh[3][1], bf1, acc3);

        // rotating wave: raw logit-diff for step v-1 (softplus deferred)
        if (v >= 1 && w == (v & 3)) {
            f32x4 da = (f32x4){dba, dba, dba, dba};
            da = MFMA16(awd[0], bf0, da);
            da = MFMA16(awd[1], bf1, da);
            if (lane < 16) DBUF[v - 1][n] = (_Float16)da[0];
        }

        // C-init for next iter (off-chain)
        const float sel = (float)((tokm_next >> n) & 1u);
        #pragma unroll
        for (int g = 0; g < 4; ++g)
            #pragma unroll
            for (int r = 0; r < 4; ++r)
                ci[g][r] = fmaf(sel, dpv[g][r], p0v[g][r]);

        // activations (g-gate clamp dropped: |acc2| < ~60 < 126, exp2 safe)
        #pragma unroll
        for (int r = 0; r < 4; ++r) {
            float ei = __builtin_amdgcn_exp2f(acc0[r]);               // e^{-i}
            float ef = __builtin_amdgcn_exp2f(acc1[r]);               // e^{-f}
            float eg = __builtin_amdgcn_exp2f(acc2[r]);               // e^{2g}
            float eo = __builtin_amdgcn_exp2f(acc3[r]);               // e^{-o}
            float Rf  = __builtin_amdgcn_rcpf(1.0f + ef);
            float Rig = __builtin_amdgcn_rcpf((1.0f + ei) * (eg + 1.0f));
            float cn  = fmaf(c4[r], Rf, (eg - 1.0f) * Rig);
            c4[r] = cn;
            float ec = __builtin_amdgcn_exp2f(fminf(cn * (2.0f * LOG2E), 60.f));
            float Ro = __builtin_amdgcn_rcpf((1.0f + eo) * (ec + 1.0f));
            h4[r] = (ec - 1.0f) * Ro;
        }
    }

    // ---- tail: publish h_512 into buffer 1 (free after last iter p=0) ----
    HhD[1][wAddr]      = pkrtz(h4[0], h4[1]);
    HhD[1][wAddr + 32] = pkrtz(h4[2], h4[3]);
    __syncthreads();

    // ---- amp post-pass ----
    {
        const int nn = tid & 15;
        const int ch = tid >> 4;
        float a = 0.0f;
        #pragma unroll 4
        for (int k = 0; k < 32; ++k) {
            int t = ch * 32 + k;
            float d = (float)DBUF[t][nn];
            float x = SRAW[nn][t] ? -d : d;
            float e = __builtin_amdgcn_exp2f(-fabsf(x) * LOG2E);
            a += fmaxf(x, 0.0f) + __builtin_amdgcn_logf(1.0f + e) * LN2;
        }
        PART[ch][nn] = a;
    }
    __syncthreads();

    if (tid < 16) {
        float ssum = 0.0f;
        #pragma unroll
        for (int c = 0; c < 16; ++c) ssum += PART[c][tid];
        out[b0s + tid] = -0.5f * ssum;              // planar real
    }

    // ---- phase: wave 0; lane (n,q) covers features 16q..16q+15 of sample n
    if (w == 0) {
        // chunk 2q: dwords n + 32j + 128q ; chunk 2q+1: +16
        float ph = 0.0f;
        #pragma unroll
        for (int j = 0; j < 4; ++j) {
            unsigned int ua = HhD[1][n + 32 * j + 128 * q];
            unsigned int ub = HhD[1][n + 16 + 32 * j + 128 * q];
            f16x2 ha  = __builtin_bit_cast(f16x2, ua);
            f16x2 hb2 = __builtin_bit_cast(f16x2, ub);
            ph = fmaf((float)ha[0], Wp[16 * q + 2 * j],
                 fmaf((float)ha[1], Wp[16 * q + 2 * j + 1], ph));
            ph = fmaf((float)hb2[0], Wp[16 * q + 8 + 2 * j],
                 fmaf((float)hb2[1], Wp[16 * q + 8 + 2 * j + 1], ph));
        }
        ph += __shfl_xor(ph, 16, 64);
        ph += __shfl_xor(ph, 32, 64);
        if (q == 0) out[B_TOT + b0s + n] = ph + bp[0];   // planar imag
    }
}

extern "C" void kernel_launch(void* const* d_in, const int* in_sizes, int n_in,
                              void* d_out, int out_size, void* d_ws, size_t ws_size,
                              hipStream_t stream) {
    const int*   s  = (const int*)  d_in[0];
    const float* W0 = (const float*)d_in[1];
    const float* b0 = (const float*)d_in[2];
    const float* Wi = (const float*)d_in[3];
    const float* Wh = (const float*)d_in[4];
    const float* bh = (const float*)d_in[5];
    const float* Wa = (const float*)d_in[6];
    const float* ba = (const float*)d_in[7];
    const float* Wp = (const float*)d_in[8];
    const float* bp = (const float*)d_in[9];
    float* out = (float*)d_out;

    dim3 grid(B_TOT / NS);   // 128 WGs × 4 waves: best measured topology (R5)
    dim3 block(256);
    lstm_bank_kernel<<<grid, block, 0, stream>>>(s, W0, b0, Wi, Wh, bh,
                                                 Wa, ba, Wp, bp, out);
}

// Round 11
// 334.286 us; speedup vs baseline: 1.4743x; 1.0142x over previous
//
#include <hip/hip_runtime.h>
#include <math.h>

typedef _Float16 f16x8 __attribute__((ext_vector_type(8)));
typedef float    f32x4 __attribute__((ext_vector_type(4)));
typedef _Float16 f16x2 __attribute__((ext_vector_type(2)));
typedef __fp16   fp16x2 __attribute__((ext_vector_type(2)));

#define B_TOT 2048
#define LSEQ  512
#define NS    16
#define LOG2E 1.44269504088896f
#define LN2   0.69314718055995f

#define MFMA16(A, B, C) __builtin_amdgcn_mfma_f32_16x16x32_f16((A), (B), (C), 0, 0, 0)

__device__ __forceinline__ unsigned int pkrtz(float a, float b) {
    fp16x2 p = __builtin_amdgcn_cvt_pkrtz(a, b);
    return __builtin_bit_cast(unsigned int, p);
}

__global__ __launch_bounds__(256, 1)
void lstm_fuse_kernel(const int* __restrict__ s,
                      const float* __restrict__ W0, const float* __restrict__ b0,
                      const float* __restrict__ Wi, const float* __restrict__ Wh,
                      const float* __restrict__ bh, const float* __restrict__ Wa,
                      const float* __restrict__ ba, const float* __restrict__ Wp,
                      const float* __restrict__ bp, float* __restrict__ out)
{
    const int tid  = threadIdx.x;
    const int w    = tid >> 6;     // wave 0..3: feature block 16w..16w+15 (all 4 gates)
    const int lane = tid & 63;
    const int n    = lane & 15;    // sample (MFMA N / D-col)
    const int q    = lane >> 4;
    const int b0s  = blockIdx.x * NS;

    // h layout: chunk c (features 8c..8c+7) of sample n = 4 consecutive dwords
    // (feature pairs) at 4n + 64*(c&1) + 128*(c>>1).
    // -> publish = 1 ds_write_b64, B-frag = 1 ds_read_b128, start banks 4*(n%8):
    //    <=2 lanes/bank per 128B phase = conflict-free (m136).
    __shared__ __align__(16) unsigned int HhD[2][512];  //  4 KB
    __shared__ unsigned short TOKB[LSEQ + 2];           //  1 KB
    __shared__ unsigned char  SRAW[NS][LSEQ];           //  8 KB
    __shared__ _Float16 DBUF[LSEQ][NS];                 // 16 KB
    __shared__ float PART[16][NS];                      //  1 KB

    // ---- stage tokens (coalesced in t) ----
    for (int i = tid; i < NS * LSEQ; i += 256)
        SRAW[i >> 9][i & 511] = (unsigned char)s[(b0s + (i >> 9)) * LSEQ + (i & 511)];
    __syncthreads();
    for (int u = tid; u <= LSEQ; u += 256) {
        unsigned int mask = 0;
        if (u >= 1) {
            #pragma unroll
            for (int m = 0; m < NS; ++m)
                mask |= ((unsigned int)SRAW[m][u - 1]) << m;
        }
        TOKB[u] = (unsigned short)mask;
    }

    // ---- A-frags: scaled Wh^T ----
    f16x8 awh[4][2];
    #pragma unroll
    for (int g = 0; g < 4; ++g) {
        const float sc  = (g == 2) ? (2.0f * LOG2E) : (-LOG2E);
        const int   col = 64 * g + 16 * w + n;
        #pragma unroll
        for (int c = 0; c < 2; ++c)
            #pragma unroll
            for (int j = 0; j < 8; ++j)
                awh[g][c][j] = (_Float16)(Wh[(32 * c + 8 * q + j) * 256 + col] * sc);
    }

    // ---- d-GEMM A-frag: row 0 = Wa[:,1]-Wa[:,0] ----
    f16x8 awd[2];
    #pragma unroll
    for (int c = 0; c < 2; ++c)
        #pragma unroll
        for (int j = 0; j < 8; ++j) {
            int k = 32 * c + 8 * q + j;
            awd[c][j] = (_Float16)((n == 0) ? (Wa[2 * k + 1] - Wa[2 * k]) : 0.0f);
        }
    const float dba = ba[1] - ba[0];

    // ---- p0/dp (scaled) ----
    float p0v[4][4], dpv[4][4];
    {
        float a0[4][4], a1[4][4];
        #pragma unroll
        for (int g = 0; g < 4; ++g)
            #pragma unroll
            for (int r = 0; r < 4; ++r) {
                float bb = bh[64 * g + 16 * w + 4 * q + r];
                a0[g][r] = bb; a1[g][r] = bb;
            }
        for (int f = 0; f < 64; ++f) {
            float wb0 = W0[f]      + b0[f];
            float wb1 = W0[64 + f] + b0[f];
            #pragma unroll
            for (int g = 0; g < 4; ++g) {
                const float4 wi4 = *(const float4*)&Wi[f * 256 + 64 * g + 16 * w + 4 * q];
                #pragma unroll
                for (int r = 0; r < 4; ++r) {
                    float wi = (&wi4.x)[r];
                    a0[g][r] = fmaf(wb0, wi, a0[g][r]);
                    a1[g][r] = fmaf(wb1, wi, a1[g][r]);
                }
            }
        }
        #pragma unroll
        for (int g = 0; g < 4; ++g) {
            const float sc = (g == 2) ? (2.0f * LOG2E) : (-LOG2E);
            #pragma unroll
            for (int r = 0; r < 4; ++r) {
                p0v[g][r] = a0[g][r] * sc;
                dpv[g][r] = (a1[g][r] - a0[g][r]) * sc;
            }
        }
    }

    __syncthreads();   // TOKB ready

    // ---- loop-invariant LDS dword addresses ----
    // publish: chunk c=2w+(q>>1), dword pair 2*(q&1): addr even -> b64
    const int wAddr = 4 * n + 64 * (q >> 1) + 128 * w + 2 * (q & 1);
    // read: bf0 = chunk q (4 dwords), bf1 = chunk 4+q = +256
    const int rAddr = 4 * n + 64 * (q & 1) + 128 * (q >> 1);

    // ---- state ----
    float h4[4] = {0, 0, 0, 0}, c4[4] = {0, 0, 0, 0};
    f32x4 ci[4];
    #pragma unroll
    for (int g = 0; g < 4; ++g)
        ci[g] = (f32x4){p0v[g][0], p0v[g][1], p0v[g][2], p0v[g][3]};

    #pragma unroll 2
    for (int v = 0; v <= LSEQ; ++v) {
        const int p = v & 1;
        unsigned int* __restrict__ hb = &HhD[p][0];

        // publish h_{v-1}: one ds_write_b64
        uint2 hw;
        hw.x = pkrtz(h4[0], h4[1]);
        hw.y = pkrtz(h4[2], h4[3]);
        *(uint2*)&hb[wAddr] = hw;
        __syncthreads();

        // B-frags: two ds_read_b128
        uint4 r0 = *(const uint4*)&hb[rAddr];
        uint4 r1 = *(const uint4*)&hb[rAddr + 256];
        const f16x8 bf0 = __builtin_bit_cast(f16x8, r0);
        const f16x8 bf1 = __builtin_bit_cast(f16x8, r1);

        const unsigned int tokm_next = (v < LSEQ) ? (unsigned int)TOKB[v + 1] : 0u;

        // gates GEMM
        f32x4 acc0 = ci[0], acc1 = ci[1], acc2 = ci[2], acc3 = ci[3];
        acc0 = MFMA16(awh[0][0], bf0, acc0);
        acc1 = MFMA16(awh[1][0], bf0, acc1);
        acc2 = MFMA16(awh[2][0], bf0, acc2);
        acc3 = MFMA16(awh[3][0], bf0, acc3);
        acc0 = MFMA16(awh[0][1], bf1, acc0);
        acc1 = MFMA16(awh[1][1], bf1, acc1);
        acc2 = MFMA16(awh[2][1], bf1, acc2);
        acc3 = MFMA16(awh[3][1], bf1, acc3);

        // rotating wave: raw logit-diff for step v-1 (softplus deferred)
        if (v >= 1 && w == (v & 3)) {
            f32x4 da = (f32x4){dba, dba, dba, dba};
            da = MFMA16(awd[0], bf0, da);
            da = MFMA16(awd[1], bf1, da);
            if (lane < 16) DBUF[v - 1][n] = (_Float16)da[0];
        }

        // C-init for next iter (off-chain)
        const float sel = (float)((tokm_next >> n) & 1u);
        #pragma unroll
        for (int g = 0; g < 4; ++g)
            #pragma unroll
            for (int r = 0; r < 4; ++r)
                ci[g][r] = fmaf(sel, dpv[g][r], p0v[g][r]);

        // activations: 5 exp2 + 2 rcp per row (single-rcp c-update)
        #pragma unroll
        for (int r = 0; r < 4; ++r) {
            float ei = __builtin_amdgcn_exp2f(acc0[r]);               // e^{-i}
            float ef = __builtin_amdgcn_exp2f(acc1[r]);               // e^{-f}
            float eg = __builtin_amdgcn_exp2f(fminf(acc2[r], 60.f));  // e^{2g}
            float eo = __builtin_amdgcn_exp2f(acc3[r]);               // e^{-o}
            float P  = (1.0f + ei) * (eg + 1.0f);
            float F  = 1.0f + ef;
            float R2 = __builtin_amdgcn_rcpf(P * F);
            float cn = fmaf(c4[r] * P, R2, (eg - 1.0f) * F * R2);
            c4[r] = cn;
            float ec = __builtin_amdgcn_exp2f(fminf(cn * (2.0f * LOG2E), 60.f));
            float Ro = __builtin_amdgcn_rcpf((1.0f + eo) * (ec + 1.0f));
            h4[r] = (ec - 1.0f) * Ro;
        }
    }

    // ---- tail: publish h_512 into buffer 1 (free: last iter used p=0) ----
    {
        uint2 hw;
        hw.x = pkrtz(h4[0], h4[1]);
        hw.y = pkrtz(h4[2], h4[3]);
        *(uint2*)&HhD[1][wAddr] = hw;
    }
    __syncthreads();

    // ---- amp post-pass ----
    {
        const int nn = tid & 15;
        const int ch = tid >> 4;
        float a = 0.0f;
        #pragma unroll 4
        for (int k = 0; k < 32; ++k) {
            int t = ch * 32 + k;
            float d = (float)DBUF[t][nn];
            float x = SRAW[nn][t] ? -d : d;
            float e = __builtin_amdgcn_exp2f(-fabsf(x) * LOG2E);
            a += fmaxf(x, 0.0f) + __builtin_amdgcn_logf(1.0f + e) * LN2;
        }
        PART[ch][nn] = a;
    }
    __syncthreads();

    if (tid < 16) {
        float ssum = 0.0f;
        #pragma unroll
        for (int c = 0; c < 16; ++c) ssum += PART[c][tid];
        out[b0s + tid] = -0.5f * ssum;              // planar real
    }

    // ---- phase: wave 0; lane (n,q) covers features 16q..16q+15 of sample n
    if (w == 0) {
        // chunk 2q at 4n+128q (+d), chunk 2q+1 at 4n+64+128q (+d)
        float ph = 0.0f;
        #pragma unroll
        for (int d = 0; d < 4; ++d) {
            unsigned int ua = HhD[1][4 * n + 128 * q + d];
            unsigned int ub = HhD[1][4 * n + 64 + 128 * q + d];
            f16x2 ha  = __builtin_bit_cast(f16x2, ua);
            f16x2 hb2 = __builtin_bit_cast(f16x2, ub);
            ph = fmaf((float)ha[0], Wp[16 * q + 2 * d],
                 fmaf((float)ha[1], Wp[16 * q + 2 * d + 1], ph));
            ph = fmaf((float)hb2[0], Wp[16 * q + 8 + 2 * d],
                 fmaf((float)hb2[1], Wp[16 * q + 8 + 2 * d + 1], ph));
        }
        ph += __shfl_xor(ph, 16, 64);
        ph += __shfl_xor(ph, 32, 64);
        if (q == 0) out[B_TOT + b0s + n] = ph + bp[0];   // planar imag
    }
}

extern "C" void kernel_launch(void* const* d_in, const int* in_sizes, int n_in,
                              void* d_out, int out_size, void* d_ws, size_t ws_size,
                              hipStream_t stream) {
    const int*   s  = (const int*)  d_in[0];
    const float* W0 = (const float*)d_in[1];
    const float* b0 = (const float*)d_in[2];
    const float* Wi = (const float*)d_in[3];
    const float* Wh = (const float*)d_in[4];
    const float* bh = (const float*)d_in[5];
    const float* Wa = (const float*)d_in[6];
    const float* ba = (const float*)d_in[7];
    const float* Wp = (const float*)d_in[8];
    const float* bp = (const float*)d_in[9];
    float* out = (float*)d_out;

    dim3 grid(B_TOT / NS);   // 128 WGs × 4 waves: forced topology (16-sample MFMA chains)
    dim3 block(256);
    lstm_fuse_kernel<<<grid, block, 0, stream>>>(s, W0, b0, Wi, Wh, bh,
                                                 Wa, ba, Wp, bp, out);
}

// Round 12
// 323.528 us; speedup vs baseline: 1.5233x; 1.0332x over previous
//
#include <hip/hip_runtime.h>
#include <math.h>

typedef _Float16 f16x8 __attribute__((ext_vector_type(8)));
typedef float    f32x4 __attribute__((ext_vector_type(4)));
typedef _Float16 f16x2 __attribute__((ext_vector_type(2)));
typedef __fp16   fp16x2 __attribute__((ext_vector_type(2)));

#define B_TOT 2048
#define LSEQ  512
#define NS    16
#define LOG2E 1.44269504088896f
#define LN2   0.69314718055995f

#define MFMA16(A, B, C) __builtin_amdgcn_mfma_f32_16x16x32_f16((A), (B), (C), 0, 0, 0)

__device__ __forceinline__ unsigned int pkrtz(float a, float b) {
    fp16x2 p = __builtin_amdgcn_cvt_pkrtz(a, b);
    return __builtin_bit_cast(unsigned int, p);
}

__global__ __launch_bounds__(256, 1)
void lstm_final_kernel(const int* __restrict__ s,
                       const float* __restrict__ W0, const float* __restrict__ b0,
                       const float* __restrict__ Wi, const float* __restrict__ Wh,
                       const float* __restrict__ bh, const float* __restrict__ Wa,
                       const float* __restrict__ ba, const float* __restrict__ Wp,
                       const float* __restrict__ bp, float* __restrict__ out)
{
    const int tid  = threadIdx.x;
    const int w    = tid >> 6;     // wave 0..3: feature block 16w..16w+15 (all 4 gates)
    const int lane = tid & 63;
    const int n    = lane & 15;    // sample (MFMA N / D-col)
    const int q    = lane >> 4;
    const int b0s  = blockIdx.x * NS;

    // h layout: chunk c (features 8c..8c+7) of sample n = 4 consecutive dwords
    // at 4n + 64*(c&1) + 128*(c>>1) -> publish 1x ds_write_b64, read 2x b128,
    // <=2 lanes/bank per phase (free, m136).
    __shared__ __align__(16) unsigned int HhD[2][512];  //  4 KB
    __shared__ unsigned short TOKB[LSEQ + 2];           //  1 KB
    __shared__ unsigned char  SRAW[NS][LSEQ];           //  8 KB
    __shared__ _Float16 DBUF[LSEQ][NS];                 // 16 KB
    __shared__ float PART[16][NS];                      //  1 KB

    // ---- stage tokens (coalesced in t) ----
    for (int i = tid; i < NS * LSEQ; i += 256)
        SRAW[i >> 9][i & 511] = (unsigned char)s[(b0s + (i >> 9)) * LSEQ + (i & 511)];
    __syncthreads();
    for (int u = tid; u <= LSEQ; u += 256) {
        unsigned int mask = 0;
        if (u >= 1) {
            #pragma unroll
            for (int m = 0; m < NS; ++m)
                mask |= ((unsigned int)SRAW[m][u - 1]) << m;
        }
        TOKB[u] = (unsigned short)mask;
    }

    // ---- A-frags: scaled Wh^T ----
    f16x8 awh[4][2];
    #pragma unroll
    for (int g = 0; g < 4; ++g) {
        const float sc  = (g == 2) ? (2.0f * LOG2E) : (-LOG2E);
        const int   col = 64 * g + 16 * w + n;
        #pragma unroll
        for (int c = 0; c < 2; ++c)
            #pragma unroll
            for (int j = 0; j < 8; ++j)
                awh[g][c][j] = (_Float16)(Wh[(32 * c + 8 * q + j) * 256 + col] * sc);
    }

    // ---- d-GEMM A-frag: row 0 = Wa[:,1]-Wa[:,0] ----
    f16x8 awd[2];
    #pragma unroll
    for (int c = 0; c < 2; ++c)
        #pragma unroll
        for (int j = 0; j < 8; ++j) {
            int k = 32 * c + 8 * q + j;
            awd[c][j] = (_Float16)((n == 0) ? (Wa[2 * k + 1] - Wa[2 * k]) : 0.0f);
        }
    const float dba = ba[1] - ba[0];

    // ---- p0/dp (scaled) ----
    float p0v[4][4], dpv[4][4];
    {
        float a0[4][4], a1[4][4];
        #pragma unroll
        for (int g = 0; g < 4; ++g)
            #pragma unroll
            for (int r = 0; r < 4; ++r) {
                float bb = bh[64 * g + 16 * w + 4 * q + r];
                a0[g][r] = bb; a1[g][r] = bb;
            }
        for (int f = 0; f < 64; ++f) {
            float wb0 = W0[f]      + b0[f];
            float wb1 = W0[64 + f] + b0[f];
            #pragma unroll
            for (int g = 0; g < 4; ++g) {
                const float4 wi4 = *(const float4*)&Wi[f * 256 + 64 * g + 16 * w + 4 * q];
                #pragma unroll
                for (int r = 0; r < 4; ++r) {
                    float wi = (&wi4.x)[r];
                    a0[g][r] = fmaf(wb0, wi, a0[g][r]);
                    a1[g][r] = fmaf(wb1, wi, a1[g][r]);
                }
            }
        }
        #pragma unroll
        for (int g = 0; g < 4; ++g) {
            const float sc = (g == 2) ? (2.0f * LOG2E) : (-LOG2E);
            #pragma unroll
            for (int r = 0; r < 4; ++r) {
                p0v[g][r] = a0[g][r] * sc;
                dpv[g][r] = (a1[g][r] - a0[g][r]) * sc;
            }
        }
    }

    __syncthreads();   // TOKB ready

    // ---- loop-invariant LDS dword addresses ----
    const int wAddr = 4 * n + 64 * (q >> 1) + 128 * w + 2 * (q & 1);
    const int rAddr = 4 * n + 64 * (q & 1) + 128 * (q >> 1);

    // ---- state ----
    float h4[4] = {0, 0, 0, 0}, c4[4] = {0, 0, 0, 0};
    f32x4 ci[4];
    #pragma unroll
    for (int g = 0; g < 4; ++g)
        ci[g] = (f32x4){p0v[g][0], p0v[g][1], p0v[g][2], p0v[g][3]};

    // deferred d-result (written one step late, off the straggler's barrier path)
    float dpend = 0.0f;
    int   tpend = -1;

    #pragma unroll 2
    for (int v = 0; v <= LSEQ; ++v) {
        const int p = v & 1;
        unsigned int* __restrict__ hb = &HhD[p][0];

        // publish h_{v-1}: one ds_write_b64
        uint2 hw;
        hw.x = pkrtz(h4[0], h4[1]);
        hw.y = pkrtz(h4[2], h4[3]);
        *(uint2*)&hb[wAddr] = hw;
        __syncthreads();

        // flush last rotation's d-result (visibility deadline = post-loop barrier)
        if (tpend >= 0) {
            if (lane < 16) DBUF[tpend][n] = (_Float16)dpend;
            tpend = -1;
        }

        // B-frags: two ds_read_b128
        uint4 r0 = *(const uint4*)&hb[rAddr];
        uint4 r1 = *(const uint4*)&hb[rAddr + 256];
        const f16x8 bf0 = __builtin_bit_cast(f16x8, r0);
        const f16x8 bf1 = __builtin_bit_cast(f16x8, r1);

        const unsigned int tokm_next = (v < LSEQ) ? (unsigned int)TOKB[v + 1] : 0u;

        // gates GEMM
        f32x4 acc0 = ci[0], acc1 = ci[1], acc2 = ci[2], acc3 = ci[3];
        acc0 = MFMA16(awh[0][0], bf0, acc0);
        acc1 = MFMA16(awh[1][0], bf0, acc1);
        acc2 = MFMA16(awh[2][0], bf0, acc2);
        acc3 = MFMA16(awh[3][0], bf0, acc3);
        acc0 = MFMA16(awh[0][1], bf1, acc0);
        acc1 = MFMA16(awh[1][1], bf1, acc1);
        acc2 = MFMA16(awh[2][1], bf1, acc2);
        acc3 = MFMA16(awh[3][1], bf1, acc3);

        // rotating wave: raw logit-diff for step v-1; write deferred one step
        if (v >= 1 && w == (v & 3)) {
            f32x4 da = (f32x4){dba, dba, dba, dba};
            da = MFMA16(awd[0], bf0, da);
            da = MFMA16(awd[1], bf1, da);
            dpend = da[0];
            tpend = v - 1;
        }

        // C-init for next iter (off-chain)
        const float sel = (float)((tokm_next >> n) & 1u);
        #pragma unroll
        for (int g = 0; g < 4; ++g)
            #pragma unroll
            for (int r = 0; r < 4; ++r)
                ci[g][r] = fmaf(sel, dpv[g][r], p0v[g][r]);

        // activations: 5 exp2 + 2 rcp per row; g-gate clamp dropped (R10-verified:
        // |acc2| << 126), ec clamp kept (NaN guard for |c| growth)
        #pragma unroll
        for (int r = 0; r < 4; ++r) {
            float ei = __builtin_amdgcn_exp2f(acc0[r]);               // e^{-i}
            float ef = __builtin_amdgcn_exp2f(acc1[r]);               // e^{-f}
            float eg = __builtin_amdgcn_exp2f(acc2[r]);               // e^{2g}
            float eo = __builtin_amdgcn_exp2f(acc3[r]);               // e^{-o}
            float P  = (1.0f + ei) * (eg + 1.0f);
            float F  = 1.0f + ef;
            float R2 = __builtin_amdgcn_rcpf(P * F);
            float cn = fmaf(c4[r] * P, R2, (eg - 1.0f) * F * R2);
            c4[r] = cn;
            float ec = __builtin_amdgcn_exp2f(fminf(cn * (2.0f * LOG2E), 60.f));
            float Ro = __builtin_amdgcn_rcpf((1.0f + eo) * (ec + 1.0f));
            h4[r] = (ec - 1.0f) * Ro;
        }
    }

    // ---- tail: flush pending d, publish h_512 into buffer 1 ----
    if (tpend >= 0 && lane < 16) DBUF[tpend][n] = (_Float16)dpend;
    {
        uint2 hw;
        hw.x = pkrtz(h4[0], h4[1]);
        hw.y = pkrtz(h4[2], h4[3]);
        *(uint2*)&HhD[1][wAddr] = hw;
    }
    __syncthreads();

    // ---- amp post-pass ----
    {
        const int nn = tid & 15;
        const int ch = tid >> 4;
        float a = 0.0f;
        #pragma unroll 4
        for (int k = 0; k < 32; ++k) {
            int t = ch * 32 + k;
            float d = (float)DBUF[t][nn];
            float x = SRAW[nn][t] ? -d : d;
            float e = __builtin_amdgcn_exp2f(-fabsf(x) * LOG2E);
            a += fmaxf(x, 0.0f) + __builtin_amdgcn_logf(1.0f + e) * LN2;
        }
        PART[ch][nn] = a;
    }
    __syncthreads();

    if (tid < 16) {
        float ssum = 0.0f;
        #pragma unroll
        for (int c = 0; c < 16; ++c) ssum += PART[c][tid];
        out[b0s + tid] = -0.5f * ssum;              // planar real
    }

    // ---- phase: wave 0; lane (n,q) covers features 16q..16q+15 of sample n
    if (w == 0) {
        float ph = 0.0f;
        #pragma unroll
        for (int d = 0; d < 4; ++d) {
            unsigned int ua = HhD[1][4 * n + 128 * q + d];
            unsigned int ub = HhD[1][4 * n + 64 + 128 * q + d];
            f16x2 ha  = __builtin_bit_cast(f16x2, ua);
            f16x2 hb2 = __builtin_bit_cast(f16x2, ub);
            ph = fmaf((float)ha[0], Wp[16 * q + 2 * d],
                 fmaf((float)ha[1], Wp[16 * q + 2 * d + 1], ph));
            ph = fmaf((float)hb2[0], Wp[16 * q + 8 + 2 * d],
                 fmaf((float)hb2[1], Wp[16 * q + 8 + 2 * d + 1], ph));
        }
        ph += __shfl_xor(ph, 16, 64);
        ph += __shfl_xor(ph, 32, 64);
        if (q == 0) out[B_TOT + b0s + n] = ph + bp[0];   // planar imag
    }
}

extern "C" void kernel_launch(void* const* d_in, const int* in_sizes, int n_in,
                              void* d_out, int out_size, void* d_ws, size_t ws_size,
                              hipStream_t stream) {
    const int*   s  = (const int*)  d_in[0];
    const float* W0 = (const float*)d_in[1];
    const float* b0 = (const float*)d_in[2];
    const float* Wi = (const float*)d_in[3];
    const float* Wh = (const float*)d_in[4];
    const float* bh = (const float*)d_in[5];
    const float* Wa = (const float*)d_in[6];
    const float* ba = (const float*)d_in[7];
    const float* Wp = (const float*)d_in[8];
    const float* bp = (const float*)d_in[9];
    float* out = (float*)d_out;

    dim3 grid(B_TOT / NS);   // 128 WGs × 4 waves: forced topology (16-sample MFMA chains)
    dim3 block(256);
    lstm_final_kernel<<<grid, block, 0, stream>>>(s, W0, b0, Wi, Wh, bh,
                                                  Wa, ba, Wp, bp, out);
}

// Round 13
// 318.813 us; speedup vs baseline: 1.5458x; 1.0148x over previous
//
#include <hip/hip_runtime.h>
#include <math.h>

typedef _Float16 f16x8 __attribute__((ext_vector_type(8)));
typedef float    f32x4 __attribute__((ext_vector_type(4)));
typedef _Float16 f16x2 __attribute__((ext_vector_type(2)));
typedef __fp16   fp16x2 __attribute__((ext_vector_type(2)));

#define B_TOT 2048
#define LSEQ  512
#define NS    16
#define LOG2E 1.44269504088896f
#define LN2   0.69314718055995f

#define MFMA16(A, B, C) __builtin_amdgcn_mfma_f32_16x16x32_f16((A), (B), (C), 0, 0, 0)

__device__ __forceinline__ unsigned int pkrtz(float a, float b) {
    fp16x2 p = __builtin_amdgcn_cvt_pkrtz(a, b);
    return __builtin_bit_cast(unsigned int, p);
}

__global__ __launch_bounds__(256, 1)
void lstm_v13_kernel(const int* __restrict__ s,
                     const float* __restrict__ W0, const float* __restrict__ b0,
                     const float* __restrict__ Wi, const float* __restrict__ Wh,
                     const float* __restrict__ bh, const float* __restrict__ Wa,
                     const float* __restrict__ ba, const float* __restrict__ Wp,
                     const float* __restrict__ bp, float* __restrict__ out)
{
    const int tid  = threadIdx.x;
    const int w    = tid >> 6;     // wave 0..3: feature block 16w..16w+15 (all 4 gates)
    const int lane = tid & 63;
    const int n    = lane & 15;    // sample (MFMA N / D-col)
    const int q    = lane >> 4;
    const int b0s  = blockIdx.x * NS;

    // h layout: chunk c (features 8c..8c+7) of sample n = 4 consecutive dwords
    // at 4n + 64*(c&1) + 128*(c>>1) -> publish 1x ds_write_b64, read 2x b128,
    // <=2 lanes/bank per phase (free, m136).
    __shared__ __align__(16) unsigned int HhD[2][512];  //  4 KB
    __shared__ unsigned short TOKB[LSEQ + 2];           //  1 KB
    __shared__ unsigned char  SRAW[NS][LSEQ];           //  8 KB
    __shared__ _Float16 DBUF[LSEQ][NS];                 // 16 KB
    __shared__ float PART[16][NS];                      //  1 KB

    // ---- stage tokens (coalesced in t) ----
    for (int i = tid; i < NS * LSEQ; i += 256)
        SRAW[i >> 9][i & 511] = (unsigned char)s[(b0s + (i >> 9)) * LSEQ + (i & 511)];
    __syncthreads();
    for (int u = tid; u <= LSEQ; u += 256) {
        unsigned int mask = 0;
        if (u >= 1) {
            #pragma unroll
            for (int m = 0; m < NS; ++m)
                mask |= ((unsigned int)SRAW[m][u - 1]) << m;
        }
        TOKB[u] = (unsigned short)mask;
    }

    // ---- A-frags: scaled Wh^T ----
    f16x8 awh[4][2];
    #pragma unroll
    for (int g = 0; g < 4; ++g) {
        const float sc  = (g == 2) ? (2.0f * LOG2E) : (-LOG2E);
        const int   col = 64 * g + 16 * w + n;
        #pragma unroll
        for (int c = 0; c < 2; ++c)
            #pragma unroll
            for (int j = 0; j < 8; ++j)
                awh[g][c][j] = (_Float16)(Wh[(32 * c + 8 * q + j) * 256 + col] * sc);
    }

    // ---- d-GEMM A-frag: row 0 = Wa[:,1]-Wa[:,0] ----
    f16x8 awd[2];
    #pragma unroll
    for (int c = 0; c < 2; ++c)
        #pragma unroll
        for (int j = 0; j < 8; ++j) {
            int k = 32 * c + 8 * q + j;
            awd[c][j] = (_Float16)((n == 0) ? (Wa[2 * k + 1] - Wa[2 * k]) : 0.0f);
        }
    const float dba = ba[1] - ba[0];

    // ---- p0/dp (scaled), kept as f32x4 for packed-FMA C-init ----
    f32x4 p0q[4], dpq[4];
    {
        float a0[4][4], a1[4][4];
        #pragma unroll
        for (int g = 0; g < 4; ++g)
            #pragma unroll
            for (int r = 0; r < 4; ++r) {
                float bb = bh[64 * g + 16 * w + 4 * q + r];
                a0[g][r] = bb; a1[g][r] = bb;
            }
        for (int f = 0; f < 64; ++f) {
            float wb0 = W0[f]      + b0[f];
            float wb1 = W0[64 + f] + b0[f];
            #pragma unroll
            for (int g = 0; g < 4; ++g) {
                const float4 wi4 = *(const float4*)&Wi[f * 256 + 64 * g + 16 * w + 4 * q];
                #pragma unroll
                for (int r = 0; r < 4; ++r) {
                    float wi = (&wi4.x)[r];
                    a0[g][r] = fmaf(wb0, wi, a0[g][r]);
                    a1[g][r] = fmaf(wb1, wi, a1[g][r]);
                }
            }
        }
        #pragma unroll
        for (int g = 0; g < 4; ++g) {
            const float sc = (g == 2) ? (2.0f * LOG2E) : (-LOG2E);
            #pragma unroll
            for (int r = 0; r < 4; ++r) {
                p0q[g][r] = a0[g][r] * sc;
                dpq[g][r] = (a1[g][r] - a0[g][r]) * sc;
            }
        }
    }

    __syncthreads();   // TOKB ready

    // ---- loop-invariant LDS dword addresses ----
    const int wAddr = 4 * n + 64 * (q >> 1) + 128 * w + 2 * (q & 1);
    const int rAddr = 4 * n + 64 * (q & 1) + 128 * (q >> 1);

    // ---- state ----
    float h4[4] = {0, 0, 0, 0}, c4[4] = {0, 0, 0, 0};
    f32x4 ci[4];
    #pragma unroll
    for (int g = 0; g < 4; ++g) ci[g] = p0q[g];

    // deferred d-result (written one step late, off the straggler's barrier path)
    float dpend = 0.0f;
    int   tpend = -1;

    #pragma unroll 4
    for (int v = 0; v <= LSEQ; ++v) {
        const int p = v & 1;
        unsigned int* __restrict__ hb = &HhD[p][0];

        // publish h_{v-1}: one ds_write_b64
        uint2 hw;
        hw.x = pkrtz(h4[0], h4[1]);
        hw.y = pkrtz(h4[2], h4[3]);
        *(uint2*)&hb[wAddr] = hw;
        __syncthreads();

        // flush last rotation's d-result (visibility deadline = post-loop barrier)
        if (tpend >= 0) {
            if (lane < 16) DBUF[tpend][n] = (_Float16)dpend;
            tpend = -1;
        }

        // B-frags: two ds_read_b128
        uint4 r0 = *(const uint4*)&hb[rAddr];
        uint4 r1 = *(const uint4*)&hb[rAddr + 256];
        const f16x8 bf0 = __builtin_bit_cast(f16x8, r0);
        const f16x8 bf1 = __builtin_bit_cast(f16x8, r1);

        const unsigned int tokm_next = (v < LSEQ) ? (unsigned int)TOKB[v + 1] : 0u;

        // gates GEMM
        f32x4 acc0 = ci[0], acc1 = ci[1], acc2 = ci[2], acc3 = ci[3];
        acc0 = MFMA16(awh[0][0], bf0, acc0);
        acc1 = MFMA16(awh[1][0], bf0, acc1);
        acc2 = MFMA16(awh[2][0], bf0, acc2);
        acc3 = MFMA16(awh[3][0], bf0, acc3);
        acc0 = MFMA16(awh[0][1], bf1, acc0);
        acc1 = MFMA16(awh[1][1], bf1, acc1);
        acc2 = MFMA16(awh[2][1], bf1, acc2);
        acc3 = MFMA16(awh[3][1], bf1, acc3);

        // rotating wave: raw logit-diff for step v-1; write deferred one step.
        // unroll-4 makes (v & 3) a compile-time constant -> uniform compare.
        if (v >= 1 && w == (v & 3)) {
            f32x4 da = (f32x4){dba, dba, dba, dba};
            da = MFMA16(awd[0], bf0, da);
            da = MFMA16(awd[1], bf1, da);
            dpend = da[0];
            tpend = v - 1;
        }

        // C-init for next iter: vector form -> v_pk_fma_f32 (2 floats/inst)
        const float sel = (float)((tokm_next >> n) & 1u);
        const f32x4 sel4 = {sel, sel, sel, sel};
        #pragma unroll
        for (int g = 0; g < 4; ++g)
            ci[g] = dpq[g] * sel4 + p0q[g];

        // activations: 5 exp2 + 2 rcp per row (algebraic minimum)
        #pragma unroll
        for (int r = 0; r < 4; ++r) {
            float ei = __builtin_amdgcn_exp2f(acc0[r]);               // e^{-i}
            float ef = __builtin_amdgcn_exp2f(acc1[r]);               // e^{-f}
            float eg = __builtin_amdgcn_exp2f(acc2[r]);               // e^{2g}
            float eo = __builtin_amdgcn_exp2f(acc3[r]);               // e^{-o}
            float P  = (1.0f + ei) * (eg + 1.0f);
            float F  = 1.0f + ef;
            float R2 = __builtin_amdgcn_rcpf(P * F);
            float cn = fmaf(c4[r] * P, R2, (eg - 1.0f) * F * R2);
            c4[r] = cn;
            float ec = __builtin_amdgcn_exp2f(fminf(cn * (2.0f * LOG2E), 60.f));
            float Ro = __builtin_amdgcn_rcpf((1.0f + eo) * (ec + 1.0f));
            h4[r] = (ec - 1.0f) * Ro;
        }
    }

    // ---- tail: flush pending d, publish h_512 into buffer 1 ----
    if (tpend >= 0 && lane < 16) DBUF[tpend][n] = (_Float16)dpend;
    {
        uint2 hw;
        hw.x = pkrtz(h4[0], h4[1]);
        hw.y = pkrtz(h4[2], h4[3]);
        *(uint2*)&HhD[1][wAddr] = hw;
    }
    __syncthreads();

    // ---- amp post-pass ----
    {
        const int nn = tid & 15;
        const int ch = tid >> 4;
        float a = 0.0f;
        #pragma unroll 4
        for (int k = 0; k < 32; ++k) {
            int t = ch * 32 + k;
            float d = (float)DBUF[t][nn];
            float x = SRAW[nn][t] ? -d : d;
            float e = __builtin_amdgcn_exp2f(-fabsf(x) * LOG2E);
            a += fmaxf(x, 0.0f) + __builtin_amdgcn_logf(1.0f + e) * LN2;
        }
        PART[ch][nn] = a;
    }
    __syncthreads();

    if (tid < 16) {
        float ssum = 0.0f;
        #pragma unroll
        for (int c = 0; c < 16; ++c) ssum += PART[c][tid];
        out[b0s + tid] = -0.5f * ssum;              // planar real
    }

    // ---- phase: wave 0; lane (n,q) covers features 16q..16q+15 of sample n
    if (w == 0) {
        float ph = 0.0f;
        #pragma unroll
        for (int d = 0; d < 4; ++d) {
            unsigned int ua = HhD[1][4 * n + 128 * q + d];
            unsigned int ub = HhD[1][4 * n + 64 + 128 * q + d];
            f16x2 ha  = __builtin_bit_cast(f16x2, ua);
            f16x2 hb2 = __builtin_bit_cast(f16x2, ub);
            ph = fmaf((float)ha[0], Wp[16 * q + 2 * d],
                 fmaf((float)ha[1], Wp[16 * q + 2 * d + 1], ph));
            ph = fmaf((float)hb2[0], Wp[16 * q + 8 + 2 * d],
                 fmaf((float)hb2[1], Wp[16 * q + 8 + 2 * d + 1], ph));
        }
        ph += __shfl_xor(ph, 16, 64);
        ph += __shfl_xor(ph, 32, 64);
        if (q == 0) out[B_TOT + b0s + n] = ph + bp[0];   // planar imag
    }
}

extern "C" void kernel_launch(void* const* d_in, const int* in_sizes, int n_in,
                              void* d_out, int out_size, void* d_ws, size_t ws_size,
                              hipStream_t stream) {
    const int*   s  = (const int*)  d_in[0];
    const float* W0 = (const float*)d_in[1];
    const float* b0 = (const float*)d_in[2];
    const float* Wi = (const float*)d_in[3];
    const float* Wh = (const float*)d_in[4];
    const float* bh = (const float*)d_in[5];
    const float* Wa = (const float*)d_in[6];
    const float* ba = (const float*)d_in[7];
    const float* Wp = (const float*)d_in[8];
    const float* bp = (const float*)d_in[9];
    float* out = (float*)d_out;

    dim3 grid(B_TOT / NS);   // 128 WGs × 4 waves: forced topology (16-sample MFMA chains)
    dim3 block(256);
    lstm_v13_kernel<<<grid, block, 0, stream>>>(s, W0, b0, Wi, Wh, bh,
                                                Wa, ba, Wp, bp, out);
}